// Round 2
// baseline (721.140 us; speedup 1.0000x reference)
//
#include <hip/hip_runtime.h>
#include <hip/hip_bf16.h>

typedef short short8 __attribute__((ext_vector_type(8)));
typedef float floatx4 __attribute__((ext_vector_type(4)));

#define MFMA_BF16 __builtin_amdgcn_mfma_f32_16x16x32_bf16

constexpr int Tt = 40;
constexpr int Ff = 92;     // input features
constexpr int ROWS = 64;   // batch rows per block
constexpr int XS = 104;    // padded x row stride in LDS (bf16 elems); 92 data + 4 zero + 8 pad
constexpr int HS = 72;     // padded h row stride in LDS (bf16 elems)

__device__ __forceinline__ float bf2f(unsigned short u) {
  unsigned int v = ((unsigned int)u) << 16;
  return __builtin_bit_cast(float, v);
}
__device__ __forceinline__ unsigned short f2bf(float f) {
  unsigned int u = __builtin_bit_cast(unsigned int, f);
  u += 0x7fffu + ((u >> 16) & 1u);   // RNE; inputs finite
  return (unsigned short)(u >> 16);
}
__device__ __forceinline__ unsigned int pack2(float a, float b) {
  return (unsigned int)f2bf(a) | ((unsigned int)f2bf(b) << 16);
}
__device__ __forceinline__ float sigm(float x) {
  return __builtin_amdgcn_rcpf(1.f + __builtin_amdgcn_exp2f(-1.442695041f * x));
}
__device__ __forceinline__ float tanhf_(float x) {
  x = fminf(30.f, fmaxf(-30.f, x));
  float e = __builtin_amdgcn_exp2f(2.885390082f * x);
  return (e - 1.f) * __builtin_amdgcn_rcpf(e + 1.f);
}

// Fused LSTM: per block, 64 batch rows, full T loop on-chip.
// f32 inputs; on-the-fly bf16 conversion for MFMA; c-state stays f32 in regs.
// Wave w owns h-columns [w*16, w*16+16): z[:, g*64 + w*16 + (lane&15)] for all
// 4 gates, 4 M-tiles of 16 rows.
__global__ __launch_bounds__(256, 2)
void lstm_fused(const float* __restrict__ x,   // [B,T,92]
                const float* __restrict__ Wk,  // [92,256]
                const float* __restrict__ Wr,  // [64,256]
                const float* __restrict__ bi,  // [256]
                const float* __restrict__ Wd,  // [64,2]
                const float* __restrict__ bd,  // [2]
                float* __restrict__ out) {     // [B,2]
  __shared__ __align__(16) unsigned short xs[2][ROWS * XS];
  __shared__ __align__(16) unsigned short hs[2][ROWS * HS];

  const int tid = threadIdx.x;
  const int wave = tid >> 6;
  const int lane = tid & 63;
  const int l15 = lane & 15;
  const int quad = lane >> 4;
  const int block0 = blockIdx.x * ROWS;
  const int nb = wave * 16 + l15;   // h-column (0..63) this lane owns

  // ---- weight B-fragments (bf16) -> registers, kept all 40 steps ----
  // B-frag: lane holds B[k = kstep*32 + quad*8 + j][n = lane&15 slot].
  short8 wkf[3][4];  // K padded 92->96, 4 gates
  short8 wrf[2][4];  // K=64, 4 gates
#pragma unroll
  for (int ks = 0; ks < 3; ++ks)
#pragma unroll
    for (int g = 0; g < 4; ++g) {
      short8 v;
#pragma unroll
      for (int j = 0; j < 8; ++j) {
        int k = ks * 32 + quad * 8 + j;
        v[j] = (k < Ff) ? (short)f2bf(Wk[k * 256 + g * 64 + nb]) : (short)0;
      }
      wkf[ks][g] = v;
    }
#pragma unroll
  for (int ks = 0; ks < 2; ++ks)
#pragma unroll
    for (int g = 0; g < 4; ++g) {
      short8 v;
#pragma unroll
      for (int j = 0; j < 8; ++j) {
        int k = ks * 32 + quad * 8 + j;
        v[j] = (short)f2bf(Wr[k * 256 + g * 64 + nb]);
      }
      wrf[ks][g] = v;
    }
  float bias[4];
#pragma unroll
  for (int g = 0; g < 4; ++g) bias[g] = bi[g * 64 + nb];

  // ---- LDS init: zero x pad cols (elems 92..95) both bufs; zero hs[0] ----
  if (tid < 128) {
    int buf = tid >> 6, rr = tid & 63;
    ((uint2*)xs[buf])[rr * 26 + 23] = make_uint2(0u, 0u);
  }
  for (int i = tid; i < ROWS * HS / 2; i += 256) ((unsigned int*)hs[0])[i] = 0u;

  // ---- stage x_{t=0} (f32 -> bf16) into xs[0] ----
  const int xr = tid >> 2, xq = tid & 3;          // row, quarter-of-row
  const float4* xg = (const float4*)x;            // 23 float4 per (row,t)
  {
    int base = ((block0 + xr) * Tt + 0) * 23;
    uint2* dst = (uint2*)xs[0];
#pragma unroll
    for (int it = 0; it < 6; ++it) {
      int d = xq + it * 4;
      if (d < 23) {
        float4 v = xg[base + d];
        dst[xr * 26 + d] = make_uint2(pack2(v.x, v.y), pack2(v.z, v.w));
      }
    }
  }
  __syncthreads();

  float c[4][4];
#pragma unroll
  for (int m = 0; m < 4; ++m)
#pragma unroll
    for (int r = 0; r < 4; ++r) c[m][r] = 0.f;

  for (int t = 0; t < Tt; ++t) {
    const int rb = t & 1, wb = rb ^ 1;
    // prefetch x_{t+1} (f32) into registers; latency hidden by MFMA section
    float4 xpre[6];
    const bool pf = (t + 1) < Tt;
    if (pf) {
      int base = ((block0 + xr) * Tt + (t + 1)) * 23;
#pragma unroll
      for (int it = 0; it < 6; ++it) {
        int d = xq + it * 4;
        if (d < 23) xpre[it] = xg[base + d];
      }
    }

    // ---- z = x_t@Wk + h_t@Wr + b ----
    floatx4 acc[4][4];  // [gate][mtile]
#pragma unroll
    for (int g = 0; g < 4; ++g)
#pragma unroll
      for (int m = 0; m < 4; ++m) acc[g][m] = floatx4{bias[g], bias[g], bias[g], bias[g]};

#pragma unroll
    for (int ks = 0; ks < 3; ++ks) {
      short8 a[4];
#pragma unroll
      for (int m = 0; m < 4; ++m)
        a[m] = *(const short8*)&xs[rb][(m * 16 + l15) * XS + ks * 32 + quad * 8];
#pragma unroll
      for (int g = 0; g < 4; ++g)
#pragma unroll
        for (int m = 0; m < 4; ++m)
          acc[g][m] = MFMA_BF16(a[m], wkf[ks][g], acc[g][m], 0, 0, 0);
    }
#pragma unroll
    for (int ks = 0; ks < 2; ++ks) {
      short8 a[4];
#pragma unroll
      for (int m = 0; m < 4; ++m)
        a[m] = *(const short8*)&hs[rb][(m * 16 + l15) * HS + ks * 32 + quad * 8];
#pragma unroll
      for (int g = 0; g < 4; ++g)
#pragma unroll
        for (int m = 0; m < 4; ++m)
          acc[g][m] = MFMA_BF16(a[m], wrf[ks][g], acc[g][m], 0, 0, 0);
    }

    // convert+publish prefetched x tile into the other buffer (no reader until
    // after the barrier below; the buffer's last readers finished at the
    // barrier that ended step t-1)
    if (pf) {
      uint2* dst = (uint2*)xs[wb];
#pragma unroll
      for (int it = 0; it < 6; ++it) {
        int d = xq + it * 4;
        if (d < 23) {
          float4 v = xpre[it];
          dst[xr * 26 + d] = make_uint2(pack2(v.x, v.y), pack2(v.z, v.w));
        }
      }
    }

    // ---- gates + state; h_new -> hs[wb] row-major (A-layout-ready) ----
    // C/D layout: row-in-tile = quad*4 + r, col = lane&15  (m89-verified)
#pragma unroll
    for (int m = 0; m < 4; ++m)
#pragma unroll
      for (int r = 0; r < 4; ++r) {
        float ig = sigm(acc[0][m][r]);
        float fg = sigm(acc[1][m][r]);
        float gg = tanhf_(acc[2][m][r]);
        float og = sigm(acc[3][m][r]);
        float cn = fg * c[m][r] + ig * gg;
        c[m][r] = cn;
        float hn = og * tanhf_(cn);
        hs[wb][(m * 16 + quad * 4 + r) * HS + nb] = f2bf(hn);
      }
    __syncthreads();  // publish hs[wb]/xs[wb] for step t+1
  }

  // ---- head: out = sigmoid(h_final @ Wd + bd); h_final = hs[0] (T even) ----
  if (tid < 128) {
    int r = tid >> 1, cc = tid & 1;
    float a = bd[cc];
#pragma unroll 8
    for (int hh = 0; hh < 64; ++hh)
      a += bf2f(hs[0][r * HS + hh]) * Wd[hh * 2 + cc];
    out[(block0 + r) * 2 + cc] = sigm(a);
  }
}

extern "C" void kernel_launch(void* const* d_in, const int* in_sizes, int n_in,
                              void* d_out, int out_size, void* d_ws, size_t ws_size,
                              hipStream_t stream) {
  const float* x  = (const float*)d_in[0];
  const float* Wk = (const float*)d_in[1];
  const float* Wr = (const float*)d_in[2];
  const float* bi = (const float*)d_in[3];
  const float* Wd = (const float*)d_in[4];
  const float* bd = (const float*)d_in[5];
  float* out = (float*)d_out;

  const int B = in_sizes[0] / (Tt * Ff);  // 32768
  dim3 grid(B / ROWS), block(256);
  lstm_fused<<<grid, block, 0, stream>>>(x, Wk, Wr, bi, Wd, bd, out);
}

// Round 3
// 655.883 us; speedup vs baseline: 1.0995x; 1.0995x over previous
//
#include <hip/hip_runtime.h>
#include <hip/hip_bf16.h>

typedef short short8 __attribute__((ext_vector_type(8)));
typedef float floatx4 __attribute__((ext_vector_type(4)));

#define MFMA_BF16 __builtin_amdgcn_mfma_f32_16x16x32_bf16

constexpr int Tt = 40;
constexpr int Ff = 92;     // input features
constexpr int ROWS = 64;   // batch rows per block
constexpr int XS = 104;    // padded x row stride in LDS (bf16 elems); 92 data + 4 zero + 8 pad
constexpr int HS = 72;     // padded h row stride in LDS (bf16 elems)
constexpr float L2E = 1.442695041f;

__device__ __forceinline__ float bf2f(unsigned short u) {
  unsigned int v = ((unsigned int)u) << 16;
  return __builtin_bit_cast(float, v);
}
__device__ __forceinline__ unsigned short f2bf(float f) {
  unsigned int u = __builtin_bit_cast(unsigned int, f);
  u += 0x7fffu + ((u >> 16) & 1u);   // RNE; finite inputs
  return (unsigned short)(u >> 16);
}
// Truncation-pack two f32 -> bf16x2 in ONE v_perm (round-toward-zero; used
// for x only — error budget has 2x headroom over RNE).
__device__ __forceinline__ unsigned int pkperm(float a, float b) {
  return __builtin_amdgcn_perm(__builtin_bit_cast(unsigned int, b),
                               __builtin_bit_cast(unsigned int, a), 0x07060302u);
}
__device__ __forceinline__ uint2 pk4(float4 v) {
  return make_uint2(pkperm(v.x, v.y), pkperm(v.z, v.w));
}
// sigmoid-core on PRE-SCALED input: s = 1/(1+2^u), u = -log2e * z (folded
// into weights). NaN-safe: exp2->inf => rcp(inf)=0; exp2->0 => 1.
__device__ __forceinline__ float sigc(float u) {
  return __builtin_amdgcn_rcpf(1.f + __builtin_amdgcn_exp2f(u));
}

// Fused LSTM: 64 batch rows/block, full T on-chip. f32 I/O, bf16 MFMA,
// f32 c-state in registers. Wave w owns h-columns [w*16, w*16+16).
__global__ __launch_bounds__(256, 2)
void lstm_fused(const float* __restrict__ x,   // [B,T,92]
                const float* __restrict__ Wk,  // [92,256]
                const float* __restrict__ Wr,  // [64,256]
                const float* __restrict__ bi,  // [256]
                const float* __restrict__ Wd,  // [64,2]
                const float* __restrict__ bd,  // [2]
                float* __restrict__ out) {     // [B,2]
  __shared__ __align__(16) unsigned short xs[2][ROWS * XS];
  __shared__ __align__(16) unsigned short hs[2][ROWS * HS];

  const int tid = threadIdx.x;
  const int wave = tid >> 6;
  const int lane = tid & 63;
  const int l15 = lane & 15;
  const int quad = lane >> 4;
  const int block0 = blockIdx.x * ROWS;
  const int nb = wave * 16 + l15;   // h-column this lane owns

  // Gate scale folded into weights/bias: i,f,o -> -log2e; g -> -2log2e
  // (tanh(x) = 2*sigc(-2log2e*x) - 1).
  const float gsc[4] = {-L2E, -L2E, -2.f * L2E, -L2E};

  // ---- weight B-fragments (pre-scaled bf16) -> registers ----
  // B-frag: lane holds B[k = ks*32 + quad*8 + j][n = lane&15 slot].
  short8 wkf[3][4];
  short8 wrf[2][4];
#pragma unroll
  for (int ks = 0; ks < 3; ++ks)
#pragma unroll
    for (int g = 0; g < 4; ++g) {
      short8 v;
#pragma unroll
      for (int j = 0; j < 8; ++j) {
        int k = ks * 32 + quad * 8 + j;
        v[j] = (k < Ff) ? (short)f2bf(gsc[g] * Wk[k * 256 + g * 64 + nb]) : (short)0;
      }
      wkf[ks][g] = v;
    }
#pragma unroll
  for (int ks = 0; ks < 2; ++ks)
#pragma unroll
    for (int g = 0; g < 4; ++g) {
      short8 v;
#pragma unroll
      for (int j = 0; j < 8; ++j) {
        int k = ks * 32 + quad * 8 + j;
        v[j] = (short)f2bf(gsc[g] * Wr[k * 256 + g * 64 + nb]);
      }
      wrf[ks][g] = v;
    }
  float bias[4];
#pragma unroll
  for (int g = 0; g < 4; ++g) bias[g] = gsc[g] * bi[g * 64 + nb];

  // ---- LDS init: zero x pad cols (elems 92..95) both bufs; zero hs[0] ----
  if (tid < 128) {
    int buf = tid >> 6, rr = tid & 63;
    ((uint2*)xs[buf])[rr * 26 + 23] = make_uint2(0u, 0u);
  }
  for (int i = tid; i < ROWS * HS / 2; i += 256) ((unsigned int*)hs[0])[i] = 0u;

  // ---- stage x_{t=0} into xs[0] ----
  const int xr = tid >> 2, xq = tid & 3;
  const float4* xg = (const float4*)x;   // 23 float4 per (row,t)
  {
    int base = ((block0 + xr) * Tt + 0) * 23;
    uint2* dst = (uint2*)xs[0];
#pragma unroll
    for (int it = 0; it < 6; ++it) {
      int d = xq + it * 4;
      if (d < 23) dst[xr * 26 + d] = pk4(xg[base + d]);
    }
  }
  __syncthreads();

  float c[4][4];
#pragma unroll
  for (int m = 0; m < 4; ++m)
#pragma unroll
    for (int r = 0; r < 4; ++r) c[m][r] = 0.f;

  for (int t = 0; t < Tt; ++t) {
    const int rb = t & 1, wb = rb ^ 1;

    // ---- z = x_t@Wk + h_t@Wr + b (pre-scaled) ----
    floatx4 acc[4][4];  // [gate][mtile]
#pragma unroll
    for (int g = 0; g < 4; ++g)
#pragma unroll
      for (int m = 0; m < 4; ++m) acc[g][m] = floatx4{bias[g], bias[g], bias[g], bias[g]};

#pragma unroll
    for (int ks = 0; ks < 3; ++ks) {
      short8 a[4];
#pragma unroll
      for (int m = 0; m < 4; ++m)
        a[m] = *(const short8*)&xs[rb][(m * 16 + l15) * XS + ks * 32 + quad * 8];
#pragma unroll
      for (int g = 0; g < 4; ++g)
#pragma unroll
        for (int m = 0; m < 4; ++m)
          acc[g][m] = MFMA_BF16(a[m], wkf[ks][g], acc[g][m], 0, 0, 0);
    }
#pragma unroll
    for (int ks = 0; ks < 2; ++ks) {
      short8 a[4];
#pragma unroll
      for (int m = 0; m < 4; ++m)
        a[m] = *(const short8*)&hs[rb][(m * 16 + l15) * HS + ks * 32 + quad * 8];
#pragma unroll
      for (int g = 0; g < 4; ++g)
#pragma unroll
        for (int m = 0; m < 4; ++m)
          acc[g][m] = MFMA_BF16(a[m], wrf[ks][g], acc[g][m], 0, 0, 0);
    }

    // ---- prefetch x_{t+1} NOW: ~900cyc HBM latency hides under the ~1800cyc
    // gate section below; keeps xpre out of the MFMA section's live range ----
    float4 xpre[6];
    const bool pf = (t + 1) < Tt;
    if (pf) {
      int base = ((block0 + xr) * Tt + (t + 1)) * 23;
#pragma unroll
      for (int it = 0; it < 6; ++it) {
        int d = xq + it * 4;
        if (d < 23) xpre[it] = xg[base + d];
      }
    }

    // ---- gates + state; h_new -> hs[wb] (A-layout-ready row-major) ----
    // C/D layout: row-in-tile = quad*4 + r, col = lane&15 (m89-verified)
#pragma unroll
    for (int m = 0; m < 4; ++m)
#pragma unroll
      for (int r = 0; r < 4; ++r) {
        float ig = sigc(acc[0][m][r]);
        float fg = sigc(acc[1][m][r]);
        float gg = fmaf(2.f, sigc(acc[2][m][r]), -1.f);   // tanh(zg)
        float og = sigc(acc[3][m][r]);
        float cn = fmaf(fg, c[m][r], ig * gg);
        c[m][r] = cn;
        float th = fmaf(2.f, sigc(-2.f * L2E * cn), -1.f); // tanh(cn)
        hs[wb][(m * 16 + quad * 4 + r) * HS + nb] = f2bf(og * th);
      }

    // publish prefetched x tile (perm-truncate pack, 1 op/pair)
    if (pf) {
      uint2* dst = (uint2*)xs[wb];
#pragma unroll
      for (int it = 0; it < 6; ++it) {
        int d = xq + it * 4;
        if (d < 23) dst[xr * 26 + d] = pk4(xpre[it]);
      }
    }
    __syncthreads();  // publish hs[wb]/xs[wb] for step t+1
  }

  // ---- head: out = sigmoid(h_final @ Wd + bd); h_final = hs[0] (T even) ----
  if (tid < 128) {
    int r = tid >> 1, cc = tid & 1;
    float a = bd[cc];
#pragma unroll 8
    for (int hh = 0; hh < 64; ++hh)
      a += bf2f(hs[0][r * HS + hh]) * Wd[hh * 2 + cc];
    out[(block0 + r) * 2 + cc] = sigc(-L2E * a);
  }
}

extern "C" void kernel_launch(void* const* d_in, const int* in_sizes, int n_in,
                              void* d_out, int out_size, void* d_ws, size_t ws_size,
                              hipStream_t stream) {
  const float* x  = (const float*)d_in[0];
  const float* Wk = (const float*)d_in[1];
  const float* Wr = (const float*)d_in[2];
  const float* bi = (const float*)d_in[3];
  const float* Wd = (const float*)d_in[4];
  const float* bd = (const float*)d_in[5];
  float* out = (float*)d_out;

  const int B = in_sizes[0] / (Tt * Ff);  // 32768
  dim3 grid(B / ROWS), block(256);
  lstm_fused<<<grid, block, 0, stream>>>(x, Wk, Wr, bi, Wd, bd, out);
}